// Round 12
// baseline (83.403 us; speedup 1.0000x reference)
//
#include <hip/hip_runtime.h>

#define CINC 64
#define COUT 64
#define HH 32
#define WW 32
#define BB 16
#define NSPLIT 4
#define CPS 16            // cin per split

typedef __attribute__((ext_vector_type(8))) short short8;
typedef __attribute__((ext_vector_type(4))) float floatx4;

__device__ __forceinline__ unsigned short f2bf(float f) {
    union { float f; unsigned int u; } c; c.f = f;
    unsigned int r = (c.u + 0x7FFFu + ((c.u >> 16) & 1u)) >> 16;
    return (unsigned short)r;
}

// W3 layout (COALESCED, round-6 verified, UNCHANGED):
// [split(4)][ts(36)][half(2)][nt(2)][q(4)][l15(16)][e(8)] bf16, ts = tap*4+s.
// Fragment for oc-tile n (oc = n*16+l15) of step ts sits at byte offset n*1024
// within the step's 4 KB block -> one B_ISSUE4 pulls all four with imm offsets.
__global__ __launch_bounds__(256) void wt_kernel(const float* __restrict__ sw,
                                                 const float* __restrict__ sc,
                                                 short* __restrict__ W3) {
    int idx = blockIdx.x * blockDim.x + threadIdx.x;
    const int total = NSPLIT * 36 * 2 * 2 * 4 * 16 * 8;   // 294,912
    if (idx >= total) return;
    int e    = idx & 7;
    int l15  = (idx >> 3) & 15;
    int q    = (idx >> 7) & 3;
    int nt   = (idx >> 9) & 1;
    int half = (idx >> 10) & 1;
    int tsid = idx >> 11;            // 0..143 = split*36 + ts
    int ts   = tsid % 36;
    int split = tsid / 36;
    int s = ts & 3, tap = ts >> 2;
    int oc = half * 32 + nt * 16 + l15;
    int cin = split * CPS + s * 4 + q;
    int g = e;
    int kh = tap / 3, kw = tap % 3;
    float w = sw[(((oc * CINC + cin) * 8 + g) * 3 + kh) * 3 + kw] * sc[oc * CINC + cin];
    W3[idx] = (short)f2bf(w);
}

// Counted vmcnt wait tied to the four fragments about to be consumed.
#define VM_WAIT4(N, a, b, c, d)                                     \
    asm volatile("s_waitcnt vmcnt(" #N ")"                          \
                 : "+v"(a), "+v"(b), "+v"(c), "+v"(d))
// Issue one step's four B-fragment loads (4 KB contiguous, imm offsets).
#define B_ISSUE4(a, b, c, d, p)                                     \
    asm volatile("global_load_dwordx4 %0, %4, off\n\t"              \
                 "global_load_dwordx4 %1, %4, off offset:1024\n\t"  \
                 "global_load_dwordx4 %2, %4, off offset:2048\n\t"  \
                 "global_load_dwordx4 %3, %4, off offset:3072"      \
                 : "=&v"(a), "=&v"(b), "=&v"(c), "=&v"(d) : "v"(p))

// MFMA-DENSITY RESTRUCTURE (m92->m93 ladder lever, +51% there; the only
// guide-proven mechanism untried after 6 nulls on latency/TLP/phase/traffic):
// 8 waves = (split = w&3, k-half = w>>2). Each wave computes the ENTIRE 64x64
// block output: acc[rowl(2)][xh(2)][n(4)] = 16 MFMAs per k-step over 18 steps
// (s in {2*shalf, 2*shalf+1} x 9 taps). Per step: 4 ds_read (A-frag reuse 4x),
// one 4-load B-issue (B-frag reuse 4x), 16 MFMAs -> per-MFMA overhead drops
// ~2.5x; per-CU ds_reads and issues halve; MFMA count unchanged.
// B pipeline: 2 steps deep (8 loads in flight), vmcnt(4), consume-then-reissue.
// k-half merge: two-phase LDS add (shalf0 writes P, barrier, shalf1 RMW-adds),
// then the verified 4-split reduce.
__global__ __launch_bounds__(512, 2) void conv_kernel(const float* __restrict__ xin,
                                                      const short* __restrict__ W3,
                                                      float* __restrict__ out) {
    __shared__ __align__(16) char smem[139264];
    short* A = (short*)smem;   // [split][r(4)][x(34)][slot(16)][e(8)], slot = cl^(x&15)
    float* P = (float*)smem;   // [split(4)][row(128)][stride 36][x(32)] = 73.7 KB

    const int mb = blockIdx.x;
    const int b = mb >> 4;
    const int h0 = (mb & 15) * 2;
    const int t = threadIdx.x;
    const int wave = t >> 6;
    const int lane = t & 63;
    const int l15 = lane & 15;
    const int q = lane >> 4;
    const int split = wave & 3;          // cin-split (4)
    const int shalf = wave >> 2;         // k-half within split (0..1)

    // ---- B pipeline prologue: issue steps 0,1 (8 loads; overlaps staging) ----
    // Step ts (0..17): tap = ts>>1, j = ts&1, s = shalf*2+j.
    // Short-addr = split*73728 + (tap*4 + shalf*2 + j)*2048 + lane*8.
    const short* bbase = W3 + (size_t)split * 73728 + (size_t)shalf * 2 * 2048
                         + lane * 8;
    short8 pb[2][4];
    B_ISSUE4(pb[0][0], pb[0][1], pb[0][2], pb[0][3], bbase);            // ts=0
    B_ISSUE4(pb[1][0], pb[1][1], pb[1][2], pb[1][3], bbase + 2048);     // ts=1

    // ---- stage A: closed-form uniform cubic B-spline bases -> bf16 LDS ----
    for (int u = t; u < 4 * 34 * CINC; u += 512) {    // 8704 items, 17 iters
        int x34 = u % 34;
        int rc = u / 34;                 // 0..255
        int c6 = rc & 63;                // cin 0..63
        int rr = rc >> 6;
        int sp = c6 >> 4;                // which split's tile
        int cl = c6 & 15;
        int y = h0 + rr;
        float v = 0.0f;
        if (y >= 1 && y <= HH && x34 >= 1 && x34 <= WW)
            v = xin[((b * CINC + c6) * HH + (y - 1)) * WW + (x34 - 1)];
        float sv = fmaf(v, 2.5f, 5.5f);               // (v + 2.2) / 0.4
        float cf = floorf(sv);
        int c = (int)cf;
        float f = sv - cf;
        float f2 = f * f, f3 = f2 * f;
        float omf = 1.0f - f;
        float w0 = f3 * (1.0f / 6.0f);
        float w1 = (1.0f + 3.0f * f + 3.0f * f2 - 3.0f * f3) * (1.0f / 6.0f);
        float w2 = (4.0f - 6.0f * f2 + 3.0f * f3) * (1.0f / 6.0f);
        float w3 = (omf * omf * omf) * (1.0f / 6.0f);
        short o8[8];
#pragma unroll
        for (int j = 0; j < 8; ++j) {
            float bj = (j == c) ? w0 : (j == c - 1) ? w1 : (j == c - 2) ? w2
                       : (j == c - 3) ? w3 : 0.0f;
            o8[j] = (short)f2bf(bj);
        }
        *(int4*)&A[sp * 17408 + (rr * 34 + x34) * 128 + ((cl ^ (x34 & 15)) * 8)] =
            *(const int4*)o8;
    }
    __syncthreads();

    floatx4 acc[2][2][4];                // [rowl][xhalf][n]
#pragma unroll
    for (int rl = 0; rl < 2; ++rl)
#pragma unroll
        for (int xh = 0; xh < 2; ++xh)
#pragma unroll
            for (int n = 0; n < 4; ++n) acc[rl][xh][n] = (floatx4)0.f;

    const int abase = split * 17408;
    const int qs = shalf * 8 + q;        // slot = (qs + j*4) ^ (xi&15)

    // ---- main loop: 18 steps x 16 MFMAs; slot = ts&1, vmcnt(4) steady ----
#pragma unroll
    for (int ts = 0; ts < 18; ++ts) {
        const int tap = ts >> 1, j = ts & 1;
        const int kh = tap / 3, kw = tap % 3;
        const int sl = ts & 1;
        if (ts < 17) { VM_WAIT4(4, pb[sl][0], pb[sl][1], pb[sl][2], pb[sl][3]); }
        else         { VM_WAIT4(0, pb[sl][0], pb[sl][1], pb[sl][2], pb[sl][3]); }

        short8 aF[2][2];
#pragma unroll
        for (int rl = 0; rl < 2; ++rl)
#pragma unroll
            for (int xh = 0; xh < 2; ++xh) {
                const int xi = xh * 16 + l15 + kw;
                aF[rl][xh] = *(const short8*)&A[abase + ((rl + kh) * 34 + xi) * 128 +
                                                (((qs + j * 4) ^ (xi & 15)) * 8)];
            }
#pragma unroll
        for (int rl = 0; rl < 2; ++rl)
#pragma unroll
            for (int xh = 0; xh < 2; ++xh)
#pragma unroll
                for (int n = 0; n < 4; ++n)
                    acc[rl][xh][n] = __builtin_amdgcn_mfma_f32_16x16x32_bf16(
                        aF[rl][xh], pb[sl][n], acc[rl][xh][n], 0, 0, 0);

        if (ts < 16) {                    // reissue AFTER the MFMAs read pb[sl]
            const int t2 = ts + 2;
            B_ISSUE4(pb[sl][0], pb[sl][1], pb[sl][2], pb[sl][3],
                     bbase + (((t2 >> 1) * 4 + (t2 & 1)) * 2048));
        }
    }

    // ---- epilogue: k-half merge + cross-split reduce via LDS, direct write ----
    __syncthreads();   // all A reads done; safe to alias with P
    if (shalf == 0) {
#pragma unroll
        for (int rl = 0; rl < 2; ++rl)
#pragma unroll
            for (int xh = 0; xh < 2; ++xh)
#pragma unroll
                for (int n = 0; n < 4; ++n) {
                    const int row = rl * 64 + n * 16 + l15;   // 0..127
                    *(floatx4*)(P + split * 4608 + row * 36 + xh * 16 + q * 4) =
                        acc[rl][xh][n];
                }
    }
    __syncthreads();
    if (shalf == 1) {
#pragma unroll
        for (int rl = 0; rl < 2; ++rl)
#pragma unroll
            for (int xh = 0; xh < 2; ++xh)
#pragma unroll
                for (int n = 0; n < 4; ++n) {
                    const int row = rl * 64 + n * 16 + l15;
                    float* p = P + split * 4608 + row * 36 + xh * 16 + q * 4;
                    *(floatx4*)p = *(const floatx4*)p + acc[rl][xh][n];
                }
    }
    __syncthreads();
    for (int it = t; it < 1024; it += 512) {
        const int x4 = (it & 7) * 4;       // 0..28
        const int row = it >> 3;           // 0..127 = rowl*64 + ocl
        const int ocl = row & 63;
        const int hh = h0 + (row >> 6);
        const int po = row * 36 + x4;
        floatx4 v = *(const floatx4*)(P + po)
                  + *(const floatx4*)(P + 4608 + po)
                  + *(const floatx4*)(P + 2 * 4608 + po)
                  + *(const floatx4*)(P + 3 * 4608 + po);
        *(floatx4*)(out + (((size_t)b * COUT + ocl) * HH + hh) * WW + x4) = v;
    }
}

extern "C" void kernel_launch(void* const* d_in, const int* in_sizes, int n_in,
                              void* d_out, int out_size, void* d_ws, size_t ws_size,
                              hipStream_t stream) {
    const float* x  = (const float*)d_in[0];
    const float* sw = (const float*)d_in[1];
    const float* sc = (const float*)d_in[2];
    float* out = (float*)d_out;
    short* W3 = (short*)d_ws;                           // 294,912 bf16 = 576 KB

    wt_kernel<<<(294912 + 255) / 256, 256, 0, stream>>>(sw, sc, W3);
    conv_kernel<<<256, 512, 0, stream>>>(x, W3, out);
}

// Round 13
// 82.259 us; speedup vs baseline: 1.0139x; 1.0139x over previous
//
#include <hip/hip_runtime.h>

#define CINC 64
#define COUT 64
#define HH 32
#define WW 32
#define BB 16
#define NSPLIT 4
#define CPS 16            // cin per split

typedef __attribute__((ext_vector_type(8))) short short8;
typedef __attribute__((ext_vector_type(4))) float floatx4;

__device__ __forceinline__ unsigned short f2bf(float f) {
    union { float f; unsigned int u; } c; c.f = f;
    unsigned int r = (c.u + 0x7FFFu + ((c.u >> 16) & 1u)) >> 16;
    return (unsigned short)r;
}

// W3 layout (COALESCED, round-6 verified, UNCHANGED):
// [split(4)][ts(36)][half(2)][nt(2)][q(4)][l15(16)][e(8)] bf16, ts = tap*4+s.
__global__ __launch_bounds__(256) void wt_kernel(const float* __restrict__ sw,
                                                 const float* __restrict__ sc,
                                                 short* __restrict__ W3) {
    int idx = blockIdx.x * blockDim.x + threadIdx.x;
    const int total = NSPLIT * 36 * 2 * 2 * 4 * 16 * 8;   // 294,912
    if (idx >= total) return;
    int e    = idx & 7;
    int l15  = (idx >> 3) & 15;
    int q    = (idx >> 7) & 3;
    int nt   = (idx >> 9) & 1;
    int half = (idx >> 10) & 1;
    int tsid = idx >> 11;            // 0..143 = split*36 + ts
    int ts   = tsid % 36;
    int split = tsid / 36;
    int s = ts & 3, tap = ts >> 2;
    int oc = half * 32 + nt * 16 + l15;
    int cin = split * CPS + s * 4 + q;
    int g = e;
    int kh = tap / 3, kw = tap % 3;
    float w = sw[(((oc * CINC + cin) * 8 + g) * 3 + kh) * 3 + kw] * sc[oc * CINC + cin];
    W3[idx] = (short)f2bf(w);
}

// L2 pre-warm: pull W3 (576 KB) + x (4 MB) into every XCD's L2 before conv.
// The 256 MB poison fill sweeps L2+L3 each iteration and the dispatch boundary
// invalidates L2, so conv otherwise takes ~900-cyc HBM misses on every B line.
// Grid-stride across 2048 blocks -> all 8 XCDs covered. Loads kept live by a
// data-dependent (never-taken in practice) store into workspace slack.
__global__ __launch_bounds__(256) void warm_kernel(const float* __restrict__ xin,
                                                   const short* __restrict__ W3,
                                                   float* __restrict__ sink) {
    int gid = blockIdx.x * 256 + threadIdx.x;
    const int gstride = gridDim.x * 256;
    float a = 0.f;
    const floatx4* xp = (const floatx4*)xin;
    const int nx = BB * CINC * HH * WW / 4;          // 262,144 float4
    for (int i = gid; i < nx; i += gstride) {
        floatx4 v = xp[i];
        a += v.x + v.y + v.z + v.w;
    }
    const floatx4* wp = (const floatx4*)W3;
    const int nw = 294912 * 2 / 16;                  // 36,864 float4
    for (int i = gid; i < nw; i += gstride) {
        floatx4 v = wp[i];
        a += v.x + v.y + v.z + v.w;
    }
    if (a == 1234567.890123f) sink[gid & 255] = a;   // keeps loads live, ~never fires
}

// Counted vmcnt wait tied to the regs about to be consumed (true data dep).
#define VM_WAIT(N, a, b) asm volatile("s_waitcnt vmcnt(" #N ")" : "+v"(a), "+v"(b))
// Issue one step's two B-fragment loads (nt=0 at p, nt=1 at p+1024 B).
#define B_ISSUE(a, b, p)                                            \
    asm volatile("global_load_dwordx4 %0, %2, off\n\t"              \
                 "global_load_dwordx4 %1, %2, off offset:1024"      \
                 : "=&v"(a), "=&v"(b) : "v"(p))

// Fused bases + implicit-GEMM conv with in-block cin-split reduction.
// Geometry = measured-best R7/R9 (80.1 us): 256 blocks (b, row-pair), 1024 thr
// = 16 waves = 4 waves/SIMD, wave = (split=w&3, rowl=(w>>2)&1, oc-half=w>>3),
// mt=2 nt=2, 36 k-steps, plain-C A reads, in-block 4-split reduce.
// CHANGE THIS ROUND: B pipeline depth 4 -> 8 (16 loads in flight, vmcnt(14),
// consume-then-reissue). Cold-B theory: every W3 line is an HBM miss (~900 cyc
// — poison fill + dispatch-boundary L2 invalidate); depth-8 raises the covered
// latency to ~8 steps. Paired with warm_kernel above.
__global__ __launch_bounds__(1024, 4) void conv_kernel(const float* __restrict__ xin,
                                                       const short* __restrict__ W3,
                                                       float* __restrict__ out) {
    __shared__ __align__(16) char smem[139264];
    short* A = (short*)smem;   // [split][r(4)][x(34)][slot(16)][e(8)], slot = cl^(x&15)
    float* P = (float*)smem;   // [split][row(128) = rowl*64+ocl][stride 36][x(32)]

    const int mb = blockIdx.x;
    const int b = mb >> 4;
    const int h0 = (mb & 15) * 2;
    const int t = threadIdx.x;
    const int wave = t >> 6;
    const int lane = t & 63;
    const int l15 = lane & 15;
    const int q = lane >> 4;
    const int split = wave & 3;
    const int rowl = (wave >> 2) & 1;
    const int n0 = (wave >> 3) * 32;

    // ---- B pipeline prologue: issue steps 0..7 (overlaps staging VALU) ----
    const short* bbase = W3 + (size_t)split * 73728 + (size_t)(wave >> 3) * 1024
                         + lane * 8;
    short8 pb0[8], pb1[8];
#pragma unroll
    for (int g = 0; g < 8; ++g)
        B_ISSUE(pb0[g], pb1[g], bbase + g * 2048);

    // ---- stage A: closed-form uniform cubic B-spline bases -> bf16 LDS ----
    for (int u = t; u < 4 * 34 * CINC; u += 1024) {
        int x34 = u % 34;
        int rc = u / 34;                 // 0..255
        int c6 = rc & 63;                // cin 0..63
        int rr = rc >> 6;
        int sp = c6 >> 4;                // which split's tile
        int cl = c6 & 15;
        int y = h0 + rr;
        float v = 0.0f;
        if (y >= 1 && y <= HH && x34 >= 1 && x34 <= WW)
            v = xin[((b * CINC + c6) * HH + (y - 1)) * WW + (x34 - 1)];
        float sv = fmaf(v, 2.5f, 5.5f);               // (v + 2.2) / 0.4
        float cf = floorf(sv);
        int c = (int)cf;
        float f = sv - cf;
        float f2 = f * f, f3 = f2 * f;
        float omf = 1.0f - f;
        float w0 = f3 * (1.0f / 6.0f);
        float w1 = (1.0f + 3.0f * f + 3.0f * f2 - 3.0f * f3) * (1.0f / 6.0f);
        float w2 = (4.0f - 6.0f * f2 + 3.0f * f3) * (1.0f / 6.0f);
        float w3 = (omf * omf * omf) * (1.0f / 6.0f);
        short o8[8];
#pragma unroll
        for (int j = 0; j < 8; ++j) {
            float bj = (j == c) ? w0 : (j == c - 1) ? w1 : (j == c - 2) ? w2
                       : (j == c - 3) ? w3 : 0.0f;
            o8[j] = (short)f2bf(bj);
        }
        *(int4*)&A[sp * 17408 + (rr * 34 + x34) * 128 + ((cl ^ (x34 & 15)) * 8)] =
            *(const int4*)o8;
    }
    __syncthreads();

    floatx4 acc[2][2];
#pragma unroll
    for (int mt = 0; mt < 2; ++mt)
#pragma unroll
        for (int nt = 0; nt < 2; ++nt) acc[mt][nt] = (floatx4)0.f;

    const int abase = split * 17408;

#define DO_MFMAS(B0, B1)                                                        \
    _Pragma("unroll")                                                           \
    for (int mt = 0; mt < 2; ++mt) {                                            \
        const int xi = mt * 16 + l15 + kw;                                      \
        short8 aF = *(const short8*)&A[abase + ((rowl + kh) * 34 + xi) * 128 +  \
                                       (((kq * 4 + q) ^ (xi & 15)) * 8)];       \
        acc[mt][0] = __builtin_amdgcn_mfma_f32_16x16x32_bf16(aF, B0, acc[mt][0], 0, 0, 0); \
        acc[mt][1] = __builtin_amdgcn_mfma_f32_16x16x32_bf16(aF, B1, acc[mt][1], 0, 0, 0); \
    }

    // ---- main loop: 36 steps; depth-8 consume-then-reissue ----
    // slot sl = ts&7 (pipeline), kq = ts&3 (A k-quarter). Steps 0..27 reissue
    // ts+8; drain waits descend 14,12,...,0 over ts = 28..35.
#pragma unroll
    for (int ts = 0; ts < 36; ++ts) {
        const int tap = ts >> 2, kq = ts & 3;
        const int kh = tap / 3, kw = tap % 3;
        const int sl = ts & 7;
        if (ts < 29)      { VM_WAIT(14, pb0[sl], pb1[sl]); }
        else if (ts == 29){ VM_WAIT(12, pb0[sl], pb1[sl]); }
        else if (ts == 30){ VM_WAIT(10, pb0[sl], pb1[sl]); }
        else if (ts == 31){ VM_WAIT(8,  pb0[sl], pb1[sl]); }
        else if (ts == 32){ VM_WAIT(6,  pb0[sl], pb1[sl]); }
        else if (ts == 33){ VM_WAIT(4,  pb0[sl], pb1[sl]); }
        else if (ts == 34){ VM_WAIT(2,  pb0[sl], pb1[sl]); }
        else              { VM_WAIT(0,  pb0[sl], pb1[sl]); }
        DO_MFMAS(pb0[sl], pb1[sl])
        if (ts < 28) {                    // reissue AFTER the MFMAs read pb[sl]
            B_ISSUE(pb0[sl], pb1[sl], bbase + (ts + 8) * 2048);
        }
    }
#undef DO_MFMAS

    // ---- epilogue: cross-split reduce via LDS, then direct out write ----
    __syncthreads();   // all A reads done; safe to alias with P
#pragma unroll
    for (int mt = 0; mt < 2; ++mt) {
#pragma unroll
        for (int nt = 0; nt < 2; ++nt) {
            const int row = rowl * 64 + n0 + nt * 16 + l15;   // 0..127
            *(floatx4*)(P + split * 4608 + row * 36 + mt * 16 + q * 4) = acc[mt][nt];
        }
    }
    __syncthreads();
    {
        const int x4 = (t & 7) * 4;        // 0..28
        const int row = t >> 3;            // 0..127 = rowl*64 + ocl
        const int ocl = row & 63;
        const int hh = h0 + (row >> 6);
        const int po = row * 36 + x4;
        floatx4 v = *(const floatx4*)(P + po)
                  + *(const floatx4*)(P + 4608 + po)
                  + *(const floatx4*)(P + 2 * 4608 + po)
                  + *(const floatx4*)(P + 3 * 4608 + po);
        *(floatx4*)(out + (((size_t)b * COUT + ocl) * HH + hh) * WW + x4) = v;
    }
}

extern "C" void kernel_launch(void* const* d_in, const int* in_sizes, int n_in,
                              void* d_out, int out_size, void* d_ws, size_t ws_size,
                              hipStream_t stream) {
    const float* x  = (const float*)d_in[0];
    const float* sw = (const float*)d_in[1];
    const float* sc = (const float*)d_in[2];
    float* out = (float*)d_out;
    short* W3 = (short*)d_ws;                           // 294,912 bf16 = 576 KB
    float* sink = (float*)((char*)d_ws + (1 << 20));    // slack, never read

    wt_kernel<<<(294912 + 255) / 256, 256, 0, stream>>>(sw, sc, W3);
    warm_kernel<<<2048, 256, 0, stream>>>(x, W3, sink);
    conv_kernel<<<256, 1024, 0, stream>>>(x, W3, out);
}

// Round 14
// 79.777 us; speedup vs baseline: 1.0455x; 1.0311x over previous
//
#include <hip/hip_runtime.h>

#define CINC 64
#define COUT 64
#define HH 32
#define WW 32
#define BB 16
#define NSPLIT 4
#define CPS 16            // cin per split

typedef __attribute__((ext_vector_type(8))) short short8;
typedef __attribute__((ext_vector_type(4))) float floatx4;

__device__ __forceinline__ unsigned short f2bf(float f) {
    union { float f; unsigned int u; } c; c.f = f;
    unsigned int r = (c.u + 0x7FFFu + ((c.u >> 16) & 1u)) >> 16;
    return (unsigned short)r;
}

// W3 layout (COALESCED, round-6 verified):
// [split(4)][ts(36)][half(2)][nt(2)][q(4)][l15(16)][e(8)] bf16, ts = tap*4+s.
// Per (split,ts,half,nt) fragment, lane (q,l15) reads shorts [lane*8..lane*8+7]
// -> one fully-contiguous 1 KB wave read (the one change that moved conv:
// -5.5 us vs the strided [oc][q][e] layout).
__global__ __launch_bounds__(256) void wt_kernel(const float* __restrict__ sw,
                                                 const float* __restrict__ sc,
                                                 short* __restrict__ W3) {
    int idx = blockIdx.x * blockDim.x + threadIdx.x;
    const int total = NSPLIT * 36 * 2 * 2 * 4 * 16 * 8;   // 294,912
    if (idx >= total) return;
    int e    = idx & 7;
    int l15  = (idx >> 3) & 15;
    int q    = (idx >> 7) & 3;
    int nt   = (idx >> 9) & 1;
    int half = (idx >> 10) & 1;
    int tsid = idx >> 11;            // 0..143 = split*36 + ts
    int ts   = tsid % 36;
    int split = tsid / 36;
    int s = ts & 3, tap = ts >> 2;
    int oc = half * 32 + nt * 16 + l15;
    int cin = split * CPS + s * 4 + q;
    int g = e;
    int kh = tap / 3, kw = tap % 3;
    float w = sw[(((oc * CINC + cin) * 8 + g) * 3 + kh) * 3 + kw] * sc[oc * CINC + cin];
    W3[idx] = (short)f2bf(w);
}

// Counted vmcnt wait tied to the regs about to be consumed (true data dep).
#define VM_WAIT(N, a, b) asm volatile("s_waitcnt vmcnt(" #N ")" : "+v"(a), "+v"(b))
// Issue one step's two B-fragment loads (nt=0 at p, nt=1 at p+1024 B).
#define B_ISSUE(a, b, p)                                            \
    asm volatile("global_load_dwordx4 %0, %2, off\n\t"              \
                 "global_load_dwordx4 %1, %2, off offset:1024"      \
                 : "=&v"(a), "=&v"(b) : "v"(p))

// Fused bases + implicit-GEMM conv with in-block cin-split reduction.
// FINAL (measured-best) configuration after the 13-round ledger:
//   - 256 blocks (b, row-pair) x 1024 thr = 16 waves = 4 waves/SIMD
//   - wave = (split = w&3, rowl = (w>>2)&1, oc-half = w>>3); mt=2, nt=2
//   - coalesced W3, depth-4 counted-vmcnt B pipeline, copy-free
//     consume-then-reissue (PMC-verified in R8), plain-C A reads
//   - in-block 4-split LDS reduce, direct out write (no partials/reduce pass)
// Removed as measured nulls: s_sleep stagger (R9), traversal rotation (R10),
// 8-wave B-dedup (R11), 16-MFMA density (R12), depth-8 + L2 warm (R13),
// pinned A-pipeline (R7).
__global__ __launch_bounds__(1024, 4) void conv_kernel(const float* __restrict__ xin,
                                                       const short* __restrict__ W3,
                                                       float* __restrict__ out) {
    __shared__ __align__(16) char smem[139264];
    short* A = (short*)smem;   // [split][r(4)][x(34)][slot(16)][e(8)], slot = cl^(x&15)
    float* P = (float*)smem;   // [split][row(128) = rowl*64+ocl][stride 36][x(32)]

    const int mb = blockIdx.x;
    const int b = mb >> 4;
    const int h0 = (mb & 15) * 2;
    const int t = threadIdx.x;
    const int wave = t >> 6;
    const int lane = t & 63;
    const int l15 = lane & 15;
    const int q = lane >> 4;
    const int split = wave & 3;
    const int rowl = (wave >> 2) & 1;
    const int n0 = (wave >> 3) * 32;

    // ---- B pipeline prologue: issue steps 0..3 (overlaps staging VALU) ----
    const short* bbase = W3 + (size_t)split * 73728 + (size_t)(wave >> 3) * 1024
                         + lane * 8;
    short8 pb0[4], pb1[4];
#pragma unroll
    for (int g = 0; g < 4; ++g)
        B_ISSUE(pb0[g], pb1[g], bbase + g * 2048);

    // ---- stage A: closed-form uniform cubic B-spline bases -> bf16 LDS ----
    for (int u = t; u < 4 * 34 * CINC; u += 1024) {
        int x34 = u % 34;
        int rc = u / 34;                 // 0..255
        int c6 = rc & 63;                // cin 0..63
        int rr = rc >> 6;
        int sp = c6 >> 4;                // which split's tile
        int cl = c6 & 15;
        int y = h0 + rr;
        float v = 0.0f;
        if (y >= 1 && y <= HH && x34 >= 1 && x34 <= WW)
            v = xin[((b * CINC + c6) * HH + (y - 1)) * WW + (x34 - 1)];
        float sv = fmaf(v, 2.5f, 5.5f);               // (v + 2.2) / 0.4
        float cf = floorf(sv);
        int c = (int)cf;
        float f = sv - cf;
        float f2 = f * f, f3 = f2 * f;
        float omf = 1.0f - f;
        float w0 = f3 * (1.0f / 6.0f);
        float w1 = (1.0f + 3.0f * f + 3.0f * f2 - 3.0f * f3) * (1.0f / 6.0f);
        float w2 = (4.0f - 6.0f * f2 + 3.0f * f3) * (1.0f / 6.0f);
        float w3 = (omf * omf * omf) * (1.0f / 6.0f);
        short o8[8];
#pragma unroll
        for (int j = 0; j < 8; ++j) {
            float bj = (j == c) ? w0 : (j == c - 1) ? w1 : (j == c - 2) ? w2
                       : (j == c - 3) ? w3 : 0.0f;
            o8[j] = (short)f2bf(bj);
        }
        *(int4*)&A[sp * 17408 + (rr * 34 + x34) * 128 + ((cl ^ (x34 & 15)) * 8)] =
            *(const int4*)o8;
    }
    __syncthreads();

    floatx4 acc[2][2];
#pragma unroll
    for (int mt = 0; mt < 2; ++mt)
#pragma unroll
        for (int nt = 0; nt < 2; ++nt) acc[mt][nt] = (floatx4)0.f;

    const int abase = split * 17408;

#define DO_MFMAS(B0, B1)                                                        \
    _Pragma("unroll")                                                           \
    for (int mt = 0; mt < 2; ++mt) {                                            \
        const int xi = mt * 16 + l15 + kw;                                      \
        short8 aF = *(const short8*)&A[abase + ((rowl + kh) * 34 + xi) * 128 +  \
                                       (((s * 4 + q) ^ (xi & 15)) * 8)];        \
        acc[mt][0] = __builtin_amdgcn_mfma_f32_16x16x32_bf16(aF, B0, acc[mt][0], 0, 0, 0); \
        acc[mt][1] = __builtin_amdgcn_mfma_f32_16x16x32_bf16(aF, B1, acc[mt][1], 0, 0, 0); \
    }

    // ---- main loop: 36 steps = 9 taps x 4 k-quarters; consume-then-reissue ----
#pragma unroll
    for (int ts = 0; ts < 36; ++ts) {
        const int tap = ts >> 2, s = ts & 3;
        const int kh = tap / 3, kw = tap % 3;
        if (ts < 32)      { VM_WAIT(6, pb0[s], pb1[s]); }
        else if (ts == 32){ VM_WAIT(6, pb0[0], pb1[0]); }
        else if (ts == 33){ VM_WAIT(4, pb0[1], pb1[1]); }
        else if (ts == 34){ VM_WAIT(2, pb0[2], pb1[2]); }
        else              { VM_WAIT(0, pb0[3], pb1[3]); }
        DO_MFMAS(pb0[s], pb1[s])
        if (ts < 32) {                    // reissue AFTER the MFMAs read pb[s]
            B_ISSUE(pb0[s], pb1[s], bbase + (ts + 4) * 2048);
        }
    }
#undef DO_MFMAS

    // ---- epilogue: cross-split reduce via LDS, then direct out write ----
    __syncthreads();   // all A reads done; safe to alias with P
#pragma unroll
    for (int mt = 0; mt < 2; ++mt) {
#pragma unroll
        for (int nt = 0; nt < 2; ++nt) {
            const int row = rowl * 64 + n0 + nt * 16 + l15;   // 0..127
            *(floatx4*)(P + split * 4608 + row * 36 + mt * 16 + q * 4) = acc[mt][nt];
        }
    }
    __syncthreads();
    {
        const int x4 = (t & 7) * 4;        // 0..28
        const int row = t >> 3;            // 0..127 = rowl*64 + ocl
        const int ocl = row & 63;
        const int hh = h0 + (row >> 6);
        const int po = row * 36 + x4;
        floatx4 v = *(const floatx4*)(P + po)
                  + *(const floatx4*)(P + 4608 + po)
                  + *(const floatx4*)(P + 2 * 4608 + po)
                  + *(const floatx4*)(P + 3 * 4608 + po);
        *(floatx4*)(out + (((size_t)b * COUT + ocl) * HH + hh) * WW + x4) = v;
    }
}

extern "C" void kernel_launch(void* const* d_in, const int* in_sizes, int n_in,
                              void* d_out, int out_size, void* d_ws, size_t ws_size,
                              hipStream_t stream) {
    const float* x  = (const float*)d_in[0];
    const float* sw = (const float*)d_in[1];
    const float* sc = (const float*)d_in[2];
    float* out = (float*)d_out;
    short* W3 = (short*)d_ws;                           // 294,912 bf16 = 576 KB

    wt_kernel<<<(294912 + 255) / 256, 256, 0, stream>>>(sw, sc, W3);
    conv_kernel<<<256, 1024, 0, stream>>>(x, W3, out);
}